// Round 1
// baseline (147.419 us; speedup 1.0000x reference)
//
#include <hip/hip_runtime.h>
#include <hip/hip_bf16.h>
#include <math.h>

// Problem constants: B=256, V=2048, PD=1024, MD=512, H=512
typedef __attribute__((ext_vector_type(8))) short short8;
typedef __attribute__((ext_vector_type(4))) short short4v;
typedef __attribute__((ext_vector_type(4))) float float4v;

__device__ __forceinline__ short f2bf(float f) {
    union { float f; unsigned u; } x; x.f = f;
    unsigned r = (x.u + 0x7FFFu + ((x.u >> 16) & 1u)) >> 16; // RNE
    return (short)r;
}

// C[m][n] = sum_k A[m][k] * W[n][k]; t = tanh(C + bias[n]);
// T[n*M+m] = t; WT[n*M+m] = w2[n]*t.   (outputs stored [h][x] for phase-2 coalescing)
__global__ __launch_bounds__(256) void gemm_tanh(
    const float* __restrict__ A, int lda,
    const float* __restrict__ W, int ldw,
    const float* __restrict__ bias, const float* __restrict__ w2,
    int K, int M,
    float* __restrict__ T, float* __restrict__ WT)
{
    // +8 pad (72 shorts): breaks the 128B row-period so b128 frag reads are <=2-way (free)
    __shared__ short As[64][72];
    __shared__ short Bs[64][72];
    const int t = threadIdx.x;
    const int m0 = blockIdx.x * 64;
    const int n0 = blockIdx.y * 64;
    const int wave = t >> 6;
    const int lane = t & 63;
    const int wm = (wave & 1) * 32;
    const int wn = (wave >> 1) * 32;
    const int lrow = lane & 15;
    const int quad = lane >> 4;

    float4v acc[2][2];
    #pragma unroll
    for (int i = 0; i < 2; i++)
        #pragma unroll
        for (int j = 0; j < 2; j++)
            acc[i][j] = (float4v){0.f, 0.f, 0.f, 0.f};

    const int sr = t >> 2;        // staging row 0..63
    const int sc = (t & 3) * 16;  // staging col 0,16,32,48

    for (int k0 = 0; k0 < K; k0 += 64) {
        const float* ap = A + (size_t)(m0 + sr) * lda + (k0 + sc);
        const float* wp = W + (size_t)(n0 + sr) * ldw + (k0 + sc);
        #pragma unroll
        for (int ii = 0; ii < 4; ii++) {
            float4v av = *(const float4v*)(ap + ii * 4);
            float4v wv = *(const float4v*)(wp + ii * 4);
            short4v a4 = { f2bf(av.x), f2bf(av.y), f2bf(av.z), f2bf(av.w) };
            short4v w4 = { f2bf(wv.x), f2bf(wv.y), f2bf(wv.z), f2bf(wv.w) };
            *(short4v*)&As[sr][sc + ii * 4] = a4;
            *(short4v*)&Bs[sr][sc + ii * 4] = w4;
        }
        __syncthreads();
        #pragma unroll
        for (int kk = 0; kk < 64; kk += 32) {
            short8 af[2], bfr[2];
            #pragma unroll
            for (int i = 0; i < 2; i++)
                af[i] = *(const short8*)&As[wm + i * 16 + lrow][kk + quad * 8];
            #pragma unroll
            for (int j = 0; j < 2; j++)
                bfr[j] = *(const short8*)&Bs[wn + j * 16 + lrow][kk + quad * 8];
            #pragma unroll
            for (int i = 0; i < 2; i++)
                #pragma unroll
                for (int j = 0; j < 2; j++)
                    acc[i][j] = __builtin_amdgcn_mfma_f32_16x16x32_bf16(
                        af[i], bfr[j], acc[i][j], 0, 0, 0);
        }
        __syncthreads();
    }

    // D layout (verified m89/m91): col(n)=lane&15, row(m)=quad*4+reg
    #pragma unroll
    for (int i = 0; i < 2; i++) {
        #pragma unroll
        for (int j = 0; j < 2; j++) {
            const int n  = n0 + wn + j * 16 + lrow;
            const int mb = m0 + wm + i * 16 + quad * 4;
            const float bn  = bias ? bias[n] : 0.0f;
            const float wn2 = w2[n];
            float4v tv, wv;
            #pragma unroll
            for (int r = 0; r < 4; r++) {
                float x  = acc[i][j][r] + bn;
                float th = tanhf(x);
                tv[r] = th;
                wv[r] = wn2 * th;
            }
            *(float4v*)&T [(size_t)n * M + mb] = tv;
            *(float4v*)&WT[(size_t)n * M + mb] = wv;
        }
    }
}

// partial[z][b][v] = sum_{h in chunk z} (wta[b,h]+wtm[v,h]) / (1 + ta[b,h]*tm[v,h])
// tanh(a+m) = (ta+tm)/(1+ta*tm); w2 folded into numerators.
__global__ __launch_bounds__(256) void pair_kernel(
    const float* __restrict__ PA, const float* __restrict__ WPA,
    const float* __restrict__ TM, const float* __restrict__ WTM,
    float* __restrict__ partial)
{
    __shared__ float sPA[32][68], sWPA[32][68], sTM[32][68], sWTM[32][68];
    const int t  = threadIdx.x;
    const int v0 = blockIdx.x * 64;
    const int b0 = blockIdx.y * 64;
    const int h0 = blockIdx.z * 128;
    const int tx = t & 15;   // v group
    const int ty = t >> 4;   // b group

    float acc[4][4];
    #pragma unroll
    for (int i = 0; i < 4; i++)
        #pragma unroll
        for (int j = 0; j < 4; j++)
            acc[i][j] = 0.f;

    const int srow = t >> 3;        // 0..31
    const int scol = (t & 7) * 8;   // 0..56

    for (int hk = 0; hk < 128; hk += 32) {
        const int h = h0 + hk + srow;
        {
            const float* p0 = PA  + (size_t)h * 256  + b0 + scol;
            const float* p1 = WPA + (size_t)h * 256  + b0 + scol;
            const float* p2 = TM  + (size_t)h * 2048 + v0 + scol;
            const float* p3 = WTM + (size_t)h * 2048 + v0 + scol;
            *(float4v*)&sPA [srow][scol]     = *(const float4v*)p0;
            *(float4v*)&sPA [srow][scol + 4] = *(const float4v*)(p0 + 4);
            *(float4v*)&sWPA[srow][scol]     = *(const float4v*)p1;
            *(float4v*)&sWPA[srow][scol + 4] = *(const float4v*)(p1 + 4);
            *(float4v*)&sTM [srow][scol]     = *(const float4v*)p2;
            *(float4v*)&sTM [srow][scol + 4] = *(const float4v*)(p2 + 4);
            *(float4v*)&sWTM[srow][scol]     = *(const float4v*)p3;
            *(float4v*)&sWTM[srow][scol + 4] = *(const float4v*)(p3 + 4);
        }
        __syncthreads();
        #pragma unroll 4
        for (int hh = 0; hh < 32; hh++) {
            float4v pa4 = *(const float4v*)&sPA [hh][ty * 4];
            float4v wa4 = *(const float4v*)&sWPA[hh][ty * 4];
            float4v tm4 = *(const float4v*)&sTM [hh][tx * 4];
            float4v wm4 = *(const float4v*)&sWTM[hh][tx * 4];
            #pragma unroll
            for (int i = 0; i < 4; i++) {
                #pragma unroll
                for (int j = 0; j < 4; j++) {
                    float num = wa4[i] + wm4[j];
                    float den = __builtin_fmaf(pa4[i], tm4[j], 1.0f);
                    acc[i][j] = __builtin_fmaf(num, __builtin_amdgcn_rcpf(den), acc[i][j]);
                }
            }
        }
        __syncthreads();
    }

    const size_t pb = (size_t)blockIdx.z * (256 * 2048);
    #pragma unroll
    for (int i = 0; i < 4; i++) {
        float4v o = { acc[i][0], acc[i][1], acc[i][2], acc[i][3] };
        *(float4v*)&partial[pb + (size_t)(b0 + ty * 4 + i) * 2048 + v0 + tx * 4] = o;
    }
}

__global__ __launch_bounds__(256) void reduce_kernel(
    const float* __restrict__ partial, const float* __restrict__ b2,
    float* __restrict__ out)
{
    const int i = (blockIdx.x * 256 + threadIdx.x) * 4;
    const float bb = b2[0];
    float4v s0 = *(const float4v*)&partial[i];
    float4v s1 = *(const float4v*)&partial[524288 + i];
    float4v s2 = *(const float4v*)&partial[1048576 + i];
    float4v s3 = *(const float4v*)&partial[1572864 + i];
    float4v o = s0 + s1 + s2 + s3 + bb;
    *(float4v*)&out[i] = o;
}

extern "C" void kernel_launch(void* const* d_in, const int* in_sizes, int n_in,
                              void* d_out, int out_size, void* d_ws, size_t ws_size,
                              hipStream_t stream)
{
    const float* patient = (const float*)d_in[0]; // 256x1024
    const float* atc4    = (const float*)d_in[1]; // 2048x512
    const float* W1      = (const float*)d_in[2]; // 512x1536
    const float* b1      = (const float*)d_in[3]; // 512
    const float* w2      = (const float*)d_in[4]; // 512
    const float* b2      = (const float*)d_in[5]; // 1
    float* out = (float*)d_out;
    float* ws  = (float*)d_ws;

    // ws layout (floats): PA[512][256], WPA[512][256], TM[512][2048], WTM[512][2048],
    //                     partial[4][256][2048]  => total 17.8 MB
    float* PA      = ws;
    float* WPA     = ws + 131072;
    float* TM      = ws + 262144;
    float* WTM     = ws + 1310720;
    float* partial = ws + 2359296;

    // ta = tanh(patient @ W1p^T + b1), wta = w2*ta   (stored [h][b])
    gemm_tanh<<<dim3(4, 8), 256, 0, stream>>>(patient, 1024, W1, 1536,
                                              b1, w2, 1024, 256, PA, WPA);
    // tm = tanh(atc4 @ W1m^T), wtm = w2*tm           (stored [h][v]; b1 applied once, above)
    gemm_tanh<<<dim3(32, 8), 256, 0, stream>>>(atc4, 512, W1 + 1024, 1536,
                                               nullptr, w2, 512, 2048, TM, WTM);
    // scores partials via tanh addition identity
    pair_kernel<<<dim3(32, 4, 4), 256, 0, stream>>>(PA, WPA, TM, WTM, partial);
    // sum 4 h-chunks + b2
    reduce_kernel<<<512, 256, 0, stream>>>(partial, b2, out);
}

// Round 2
// 128.309 us; speedup vs baseline: 1.1489x; 1.1489x over previous
//
#include <hip/hip_runtime.h>
#include <hip/hip_bf16.h>
#include <math.h>

// Problem constants: B=256, V=2048, PD=1024, MD=512, H=512
typedef __attribute__((ext_vector_type(8))) short short8;
typedef __attribute__((ext_vector_type(4))) short short4v;
typedef __attribute__((ext_vector_type(4))) float float4v;

__device__ __forceinline__ short f2bf(float f) {
    union { float f; unsigned u; } x; x.f = f;
    unsigned r = (x.u + 0x7FFFu + ((x.u >> 16) & 1u)) >> 16; // RNE
    return (short)r;
}

// Fused dual GEMM + exp epilogue.
//  z==0: Ea[h][b] = exp(2*(patient@W1p^T + b1))   M=256,  K=1024
//  z==1: Em[h][v] = exp(2*(atc4@W1m^T))           M=2048, K=512
// C[m][n] = sum_k A[m][k]*W[n][k]; T[n*M+m] = exp(2*(C+bias[n]))
__global__ __launch_bounds__(256) void gemm_exp(
    const float* __restrict__ patient, const float* __restrict__ atc4,
    const float* __restrict__ W1, const float* __restrict__ b1,
    float* __restrict__ EA, float* __restrict__ EM)
{
    const float* A; const float* W; const float* bias; float* T;
    int lda, K, M;
    if (blockIdx.z == 0) {
        if (blockIdx.x >= 4) return;           // 4x8 tile grid for 256x512
        A = patient; lda = 1024; K = 1024; M = 256; bias = b1; T = EA; W = W1;
    } else {
        A = atc4;    lda = 512;  K = 512;  M = 2048; bias = nullptr; T = EM; W = W1 + 1024;
    }
    const int ldw = 1536;

    __shared__ short As[64][72];
    __shared__ short Bs[64][72];
    const int t = threadIdx.x;
    const int m0 = blockIdx.x * 64;
    const int n0 = blockIdx.y * 64;
    const int wave = t >> 6;
    const int lane = t & 63;
    const int wm = (wave & 1) * 32;
    const int wn = (wave >> 1) * 32;
    const int lrow = lane & 15;
    const int quad = lane >> 4;

    float4v acc[2][2];
    #pragma unroll
    for (int i = 0; i < 2; i++)
        #pragma unroll
        for (int j = 0; j < 2; j++)
            acc[i][j] = (float4v){0.f, 0.f, 0.f, 0.f};

    const int sr = t >> 2;        // staging row 0..63
    const int sc = (t & 3) * 16;  // staging col 0,16,32,48

    for (int k0 = 0; k0 < K; k0 += 64) {
        const float* ap = A + (size_t)(m0 + sr) * lda + (k0 + sc);
        const float* wp = W + (size_t)(n0 + sr) * ldw + (k0 + sc);
        #pragma unroll
        for (int ii = 0; ii < 4; ii++) {
            float4v av = *(const float4v*)(ap + ii * 4);
            float4v wv = *(const float4v*)(wp + ii * 4);
            short4v a4 = { f2bf(av.x), f2bf(av.y), f2bf(av.z), f2bf(av.w) };
            short4v w4 = { f2bf(wv.x), f2bf(wv.y), f2bf(wv.z), f2bf(wv.w) };
            *(short4v*)&As[sr][sc + ii * 4] = a4;
            *(short4v*)&Bs[sr][sc + ii * 4] = w4;
        }
        __syncthreads();
        #pragma unroll
        for (int kk = 0; kk < 64; kk += 32) {
            short8 af[2], bfr[2];
            #pragma unroll
            for (int i = 0; i < 2; i++)
                af[i] = *(const short8*)&As[wm + i * 16 + lrow][kk + quad * 8];
            #pragma unroll
            for (int j = 0; j < 2; j++)
                bfr[j] = *(const short8*)&Bs[wn + j * 16 + lrow][kk + quad * 8];
            #pragma unroll
            for (int i = 0; i < 2; i++)
                #pragma unroll
                for (int j = 0; j < 2; j++)
                    acc[i][j] = __builtin_amdgcn_mfma_f32_16x16x32_bf16(
                        af[i], bfr[j], acc[i][j], 0, 0, 0);
        }
        __syncthreads();
    }

    // D layout (verified m89/m91): col(n)=lane&15, row(m)=quad*4+reg
    #pragma unroll
    for (int i = 0; i < 2; i++) {
        #pragma unroll
        for (int j = 0; j < 2; j++) {
            const int n  = n0 + wn + j * 16 + lrow;
            const int mb = m0 + wm + i * 16 + quad * 4;
            const float bn = bias ? bias[n] : 0.0f;
            float4v ev;
            #pragma unroll
            for (int r = 0; r < 4; r++)
                ev[r] = __expf(2.0f * (acc[i][j][r] + bn));
            *(float4v*)&T[(size_t)n * M + mb] = ev;
        }
    }
}

// partial[z][b][v] = sum_{h in chunk z} [ w2[h] - 2*w2[h] / (1 + Ea[h][b]*Em[h][v]) ]
// (w2*tanh via  tanh(x) = 1 - 2/(1+e^{2x});  the w2[h] constant folds to a per-chunk sum)
// Tile: 64 v x 32 b x 128 h.  Grid (32, 8, 4) = 1024 blocks.
__global__ __launch_bounds__(256) void pair_kernel(
    const float* __restrict__ EA, const float* __restrict__ EM,
    const float* __restrict__ w2, float* __restrict__ partial)
{
    __shared__ float sEA[64][36];   // [h][b] half-chunk
    __shared__ float sEM[64][68];   // [h][v]
    __shared__ float sC[128];       // -2*w2[h] for the chunk
    const int t  = threadIdx.x;
    const int v0 = blockIdx.x * 64;
    const int b0 = blockIdx.y * 32;
    const int h0 = blockIdx.z * 128;
    const int tx = t & 15;   // v group: v = v0 + tx*4
    const int ty = t >> 4;   // b group: b = b0 + ty*2

    // chunk w2 sum (block-uniform -> scalarized loads), and -2*w2 into LDS
    float w2s = 0.0f;
    for (int i = 0; i < 128; i++) w2s += w2[h0 + i];
    if (t < 128) sC[t] = -2.0f * w2[h0 + t];

    float acc[2][4];
    #pragma unroll
    for (int i = 0; i < 2; i++)
        #pragma unroll
        for (int j = 0; j < 4; j++)
            acc[i][j] = 0.0f;

    const int r  = t >> 2;
    const int cA = (t & 3) * 8;
    const int cM = (t & 3) * 16;

    for (int half = 0; half < 2; half++) {
        const int hb = h0 + half * 64;
        {
            const float* pa = EA + (size_t)(hb + r) * 256 + b0 + cA;
            *(float4v*)&sEA[r][cA]     = *(const float4v*)pa;
            *(float4v*)&sEA[r][cA + 4] = *(const float4v*)(pa + 4);
            const float* pm = EM + (size_t)(hb + r) * 2048 + v0 + cM;
            *(float4v*)&sEM[r][cM]      = *(const float4v*)pm;
            *(float4v*)&sEM[r][cM + 4]  = *(const float4v*)(pm + 4);
            *(float4v*)&sEM[r][cM + 8]  = *(const float4v*)(pm + 8);
            *(float4v*)&sEM[r][cM + 12] = *(const float4v*)(pm + 12);
        }
        __syncthreads();
        #pragma unroll 2
        for (int h = 0; h < 64; h++) {
            const float ea0 = sEA[h][ty * 2];
            const float ea1 = sEA[h][ty * 2 + 1];
            const float4v em = *(const float4v*)&sEM[h][tx * 4];
            const float c = sC[half * 64 + h];
            #pragma unroll
            for (int j = 0; j < 4; j++) {
                float d0 = __builtin_fmaf(ea0, em[j], 1.0f);
                float d1 = __builtin_fmaf(ea1, em[j], 1.0f);
                acc[0][j] = __builtin_fmaf(c, __builtin_amdgcn_rcpf(d0), acc[0][j]);
                acc[1][j] = __builtin_fmaf(c, __builtin_amdgcn_rcpf(d1), acc[1][j]);
            }
        }
        __syncthreads();
    }

    const size_t pb = (size_t)blockIdx.z * (256 * 2048);
    #pragma unroll
    for (int i = 0; i < 2; i++) {
        float4v o = { acc[i][0] + w2s, acc[i][1] + w2s, acc[i][2] + w2s, acc[i][3] + w2s };
        *(float4v*)&partial[pb + (size_t)(b0 + ty * 2 + i) * 2048 + v0 + tx * 4] = o;
    }
}

__global__ __launch_bounds__(256) void reduce_kernel(
    const float* __restrict__ partial, const float* __restrict__ b2,
    float* __restrict__ out)
{
    const int i = (blockIdx.x * 256 + threadIdx.x) * 4;
    const float bb = b2[0];
    float4v s0 = *(const float4v*)&partial[i];
    float4v s1 = *(const float4v*)&partial[524288 + i];
    float4v s2 = *(const float4v*)&partial[1048576 + i];
    float4v s3 = *(const float4v*)&partial[1572864 + i];
    float4v o = s0 + s1 + s2 + s3 + bb;
    *(float4v*)&out[i] = o;
}

extern "C" void kernel_launch(void* const* d_in, const int* in_sizes, int n_in,
                              void* d_out, int out_size, void* d_ws, size_t ws_size,
                              hipStream_t stream)
{
    const float* patient = (const float*)d_in[0]; // 256x1024
    const float* atc4    = (const float*)d_in[1]; // 2048x512
    const float* W1      = (const float*)d_in[2]; // 512x1536
    const float* b1      = (const float*)d_in[3]; // 512
    const float* w2      = (const float*)d_in[4]; // 512
    const float* b2      = (const float*)d_in[5]; // 1
    float* out = (float*)d_out;
    float* ws  = (float*)d_ws;

    // ws layout (floats): EA[512][256], EM[512][2048], partial[4][256][2048] => 13.1 MB
    float* EA      = ws;
    float* EM      = ws + 131072;
    float* partial = ws + 1179648;

    // Both GEMMs in one dispatch (z selects); exp(2x) epilogue
    gemm_exp<<<dim3(32, 8, 2), 256, 0, stream>>>(patient, atc4, W1, b1, EA, EM);
    // score partials via 1/(1+Ea*Em) identity: 3 VALU ops per element
    pair_kernel<<<dim3(32, 8, 4), 256, 0, stream>>>(EA, EM, w2, partial);
    // sum 4 h-chunks + b2
    reduce_kernel<<<512, 256, 0, stream>>>(partial, b2, out);
}